// Round 3
// baseline (508.624 us; speedup 1.0000x reference)
//
#include <hip/hip_runtime.h>

// Problem constants (match reference setup_inputs)
#define H_DIM   4096   // input features (K of the GEMM)
#define M_DIM   4096   // output features (W rows = C cols)
#define N_ROWS  8192   // B*S flattened x rows
#define NNZ_ROW 2048
#define NT      (H_DIM / 64)   // 64 K-tiles of BK=64

typedef __bf16 bf16x8 __attribute__((ext_vector_type(8)));
typedef float  f32x4  __attribute__((ext_vector_type(4)));

// fp32 -> bf16 round-to-nearest-even on raw bits
__device__ __forceinline__ unsigned short f2bf(float f) {
    unsigned int u = __float_as_uint(f);
    u += 0x7fffu + ((u >> 16) & 1u);
    return (unsigned short)(u >> 16);
}

// async global->LDS, 16B/lane; LDS dst = wave-uniform base + lane*16
__device__ __forceinline__ void gld_lds16(const void* g, void* l) {
    __builtin_amdgcn_global_load_lds(
        (__attribute__((address_space(1))) const void*)g,
        (__attribute__((address_space(3))) void*)l,
        16, 0, 0);
}

#define SB() __builtin_amdgcn_sched_barrier(0)

// raw workgroup barrier with compiler fences
__device__ __forceinline__ void wg_barrier() {
    SB();
    asm volatile("" ::: "memory");
    __builtin_amdgcn_s_barrier();
    asm volatile("" ::: "memory");
    SB();
}

// rule #18: sched_barrier(0) right after an inline-asm waitcnt
#define LGKM(n) do { \
    asm volatile("s_waitcnt lgkmcnt(" #n ")" ::: "memory"); \
    SB(); \
} while (0)

#define VMCNT(n) do { \
    asm volatile("s_waitcnt vmcnt(" #n ")" ::: "memory"); \
    SB(); \
} while (0)

// ---------------------------------------------------------------------------
// Kernel 1: decode CSR directly into MFMA B-fragment-major bf16 W.
// Layout: uint4 slot = (ct*128 + kc)*64 + (jq*16 + fr), ct=m>>4, kc=k>>5,
// fr=m&15, jq=(k>>3)&3. A wave's b-frag load is 64 lanes x 16B fully linear.
// (verbatim from the 616us round-0 kernel, harness-verified)
// ---------------------------------------------------------------------------
__global__ __launch_bounds__(256) void decode_w_frag_kernel(
        const float* __restrict__ values,
        const int*   __restrict__ col_idx,
        unsigned short* __restrict__ Wf) {
    __shared__ unsigned short buf[4 * H_DIM];      // 32 KiB
    const int r4 = blockIdx.x;                     // rows 4*r4 .. 4*r4+3
    const int t  = threadIdx.x;

    uint4 z = make_uint4(0u, 0u, 0u, 0u);
    #pragma unroll
    for (int i = 0; i < 8; ++i) ((uint4*)buf)[i * 256 + t] = z;
    __syncthreads();

    #pragma unroll
    for (int rl = 0; rl < 4; ++rl) {
        const long base = ((long)(4 * r4 + rl)) * NNZ_ROW;
        #pragma unroll
        for (int j = 0; j < NNZ_ROW; j += 256) {
            float v = values[base + j + t];
            int   c = col_idx[base + j + t];
            buf[rl * H_DIM + c] = f2bf(v);
        }
    }
    __syncthreads();

    const int ct  = r4 >> 2;
    const int fr0 = (r4 & 3) * 4;
    #pragma unroll
    for (int it = 0; it < 8; ++it) {
        const int task = it * 256 + t;             // 0..2047
        const int rl = task & 3;
        const int jq = (task >> 2) & 3;
        const int kc = task >> 4;                  // 0..127
        uint4 v = *(const uint4*)&buf[rl * H_DIM + kc * 32 + jq * 8];
        const long dst = (((long)ct * 128 + kc) * 64 + jq * 16 + fr0 + rl) * 8;
        *(uint4*)&Wf[dst] = v;
    }
}

// ---------------------------------------------------------------------------
// Kernel 2: x fp32 -> bf16 row-major. float4 load (16B), 8B store, grid-stride.
// ---------------------------------------------------------------------------
__global__ __launch_bounds__(256) void convert_x_kernel(
        const float4* __restrict__ x, unsigned long long* __restrict__ xb) {
    const long total = (long)N_ROWS * H_DIM / 4;
    for (long i = (long)blockIdx.x * 256 + threadIdx.x; i < total;
         i += (long)gridDim.x * 256) {
        float4 a = x[i];
        union { unsigned short s[4]; unsigned long long v; } r;
        r.s[0] = f2bf(a.x); r.s[1] = f2bf(a.y);
        r.s[2] = f2bf(a.z); r.s[3] = f2bf(a.w);
        xb[i] = r.v;
    }
}

// ---------------------------------------------------------------------------
// Kernel 3: C[8192,4096] = Xb @ Wf^T. 256x256 tile, BK=64, 8 waves (2Mx4N).
// A: 64KB LDS double-buffer (xor-swizzled, gld_lds staged 1 tile ahead).
// B: NO LDS — fragment-major global loads 1 tile ahead into the same regs
//    (WAR-ordered after last MFMA use -> zero extra registers).
// 1 barrier/tile; all waits counted (vmcnt 8/8/4, lgkm 4/0 block-stepped);
// a-fragment ds_reads stream under the MFMA groups. XCD-bijective grid.
// ---------------------------------------------------------------------------
__global__ __launch_bounds__(512, 2) void gemm256_kernel(
        const unsigned short* __restrict__ A,    // Xb row-major [8192][4096]
        const unsigned short* __restrict__ Bf,   // W fragment-major
        float* __restrict__ C) {
    __shared__ unsigned short lds[2 * 16384];    // 64 KiB: two 256x64 A tiles

    const int t    = threadIdx.x;
    const int lane = t & 63;
    const int wid  = t >> 6;
    const int wm   = wid >> 2;        // 0..1 : 128-row slab
    const int wn   = wid & 3;         // 0..3 : 64-col slab

    // XCD swizzle: 512 blocks, 8 XCDs -> each XCD owns 2 ctiles (4MB B ~ L2)
    const int bid   = blockIdx.x;
    const int wg    = (bid & 7) * 64 + (bid >> 3);
    const int ctile = wg >> 5;        // 0..15
    const int rtile = wg & 31;        // 0..31
    const long row0 = (long)rtile * 256;
    const long col0 = (long)ctile * 256;

    // ---- A staging: thread t owns 16B chunk (row rr, chunk (t&7)^(rr&7));
    // LDS dest linear. 4 gld_lds per tile stage the full 256x64 A tile.
    const int rr = t >> 3;                       // 0..63
    const int cc = ((t & 7) ^ (rr & 7)) * 8;     // pre-swizzled source chunk
    const unsigned short* pA_ = A + (row0 + rr) * H_DIM + cc;
    unsigned short* const Ld = &lds[t * 8];

#define STAGEA(kts, nb) do { \
    const unsigned short* sp_ = pA_ + (long)(kts) * 64; \
    gld_lds16(sp_,                Ld + (nb));         \
    gld_lds16(sp_ +  64 * H_DIM,  Ld + (nb) + 4096);  \
    gld_lds16(sp_ + 128 * H_DIM,  Ld + (nb) + 8192);  \
    gld_lds16(sp_ + 192 * H_DIM,  Ld + (nb) + 12288); \
} while (0)

    // ---- B fragment loads (global, L2-resident, uniform base + lane)
    const uint4* Bu = (const uint4*)Bf;
    const int ct0 = __builtin_amdgcn_readfirstlane(ctile * 16 + wn * 4);
    union BU { uint4 u; bf16x8 v; };
    BU b0[2][2], b1[2][2];
    auto loadB = [&](BU (&bb)[2][2], int jb, int k2) {
        #pragma unroll
        for (int j = 0; j < 2; ++j)
            #pragma unroll
            for (int kk = 0; kk < 2; ++kk)
                bb[j][kk].u = Bu[(((long)(ct0 + jb + j)) * 128 + k2 + kk) * 64 + lane];
    };

    // ---- compute-side addressing (identical to verified round-1/2 kernels)
    const int fr = lane & 15;
    const int jq = lane >> 4;
    const int cx = fr & 7;
    const int off0 = ((0 * 4 + jq) ^ cx) * 8;    // kk=0 chunk, elems
    const int off1 = ((1 * 4 + jq) ^ cx) * 8;    // kk=1 chunk, elems
    const int aoff = wm * 8192 + fr * 64;

    f32x4 acc[8][4];
    #pragma unroll
    for (int i = 0; i < 8; ++i)
        #pragma unroll
        for (int j = 0; j < 4; ++j) acc[i][j] = (f32x4)0.0f;

    bf16x8 a[4][2];
    auto mm2 = [&](int ia, int ra, BU (&bb)[2][2], int jb) {
        #pragma unroll
        for (int ii = 0; ii < 2; ++ii)
            #pragma unroll
            for (int j = 0; j < 2; ++j) {
                acc[ra + ii][jb + j] = __builtin_amdgcn_mfma_f32_16x16x32_bf16(
                    a[ia + ii][0], bb[j][0].v, acc[ra + ii][jb + j], 0, 0, 0);
                acc[ra + ii][jb + j] = __builtin_amdgcn_mfma_f32_16x16x32_bf16(
                    a[ia + ii][1], bb[j][1].v, acc[ra + ii][jb + j], 0, 0, 0);
            }
    };

    // ---- prologue: A(tile0)->buf0, b(tile0) -> regs
    STAGEA(0, 0); SB();
    loadB(b0, 0, 0); SB();
    loadB(b1, 2, 0); SB();

    #pragma unroll 1
    for (int kt = 0; kt < NT; ++kt) {
        const int cur = (kt & 1) * 16384;
        const int nxt = 16384 - cur;
        int ktn = kt + 1; if (ktn == NT) ktn = 0;
        const int k2n = ktn * 2;

        // entry: A(kt) staged (issued 1 tile ago; 8 newer vmem allowed in flight)
        VMCNT(8);
        wg_barrier();
        STAGEA(ktn, nxt); SB();                  // A(kt+1) -> other buffer

        const unsigned short* Ab0 = &lds[cur + aoff + off0];
        const unsigned short* Ab1 = &lds[cur + aoff + off1];

        // ---- P1: rows 0-3 of the wave slab
        a[0][0] = *(const bf16x8*)(Ab0 + 0);
        a[0][1] = *(const bf16x8*)(Ab1 + 0);
        a[1][0] = *(const bf16x8*)(Ab0 + 1024);
        a[1][1] = *(const bf16x8*)(Ab1 + 1024);
        SB();
        a[2][0] = *(const bf16x8*)(Ab0 + 2048);
        a[2][1] = *(const bf16x8*)(Ab1 + 2048);
        a[3][0] = *(const bf16x8*)(Ab0 + 3072);
        a[3][1] = *(const bf16x8*)(Ab1 + 3072);
        SB();
        VMCNT(8);                                 // b0(kt) landed
        LGKM(4);                                  // first read block landed
        __builtin_amdgcn_s_setprio(1);
        mm2(0, 0, b0, 0);
        LGKM(0);
        mm2(2, 2, b0, 0);
        VMCNT(4);                                 // b1(kt) landed
        mm2(0, 0, b1, 2);
        mm2(2, 2, b1, 2);
        __builtin_amdgcn_s_setprio(0);
        SB();

        // ---- P2: rows 4-7 (reuse a[] regs; WAR ordered after the mms above)
        a[0][0] = *(const bf16x8*)(Ab0 + 4096);
        a[0][1] = *(const bf16x8*)(Ab1 + 4096);
        a[1][0] = *(const bf16x8*)(Ab0 + 5120);
        a[1][1] = *(const bf16x8*)(Ab1 + 5120);
        SB();
        a[2][0] = *(const bf16x8*)(Ab0 + 6144);
        a[2][1] = *(const bf16x8*)(Ab1 + 6144);
        a[3][0] = *(const bf16x8*)(Ab0 + 7168);
        a[3][1] = *(const bf16x8*)(Ab1 + 7168);
        SB();
        LGKM(4);
        __builtin_amdgcn_s_setprio(1);
        mm2(0, 4, b0, 0);
        LGKM(0);
        mm2(2, 6, b0, 0);
        __builtin_amdgcn_s_setprio(0);
        SB();
        loadB(b0, 0, k2n); SB();                  // b0 dead -> prefetch next
        __builtin_amdgcn_s_setprio(1);
        mm2(0, 4, b1, 2);
        mm2(2, 6, b1, 2);
        __builtin_amdgcn_s_setprio(0);
        SB();
        loadB(b1, 2, k2n); SB();                  // b1 dead -> prefetch next
    }

#undef STAGEA

    // ---- epilogue: D col = lane&15, row = (lane>>4)*4 + reg  [m89/m91]
    const int dcol = lane & 15;
    const int dr4  = (lane >> 4) * 4;
    const long crow = row0 + wm * 128;
    const int  ccol = (int)col0 + wn * 64 + dcol;
    #pragma unroll
    for (int i = 0; i < 8; ++i) {
        float* cp = C + (crow + i * 16 + dr4) * M_DIM + ccol;
        #pragma unroll
        for (int j = 0; j < 4; ++j)
            #pragma unroll
            for (int q = 0; q < 4; ++q)
                cp[(long)q * M_DIM + j * 16] = acc[i][j][q];
    }
}

// ---------------------------------------------------------------------------
// Fallback if ws too small: naive fp32 sparse dot (correct, slow).
// ---------------------------------------------------------------------------
__global__ __launch_bounds__(256) void naive_kernel(
        const float* __restrict__ x, const float* __restrict__ vals,
        const int* __restrict__ cols, float* __restrict__ out) {
    const long idx = blockIdx.x * 256L + threadIdx.x;
    const int  m   = (int)(idx & (M_DIM - 1));
    const long n   = idx >> 12;
    const float* xr = x + n * H_DIM;
    const float* v  = vals + (long)m * NNZ_ROW;
    const int*   c  = cols + (long)m * NNZ_ROW;
    float s = 0.f;
    for (int j = 0; j < NNZ_ROW; ++j) s += v[j] * xr[c[j]];
    out[idx] = s;
}

extern "C" void kernel_launch(void* const* d_in, const int* in_sizes, int n_in,
                              void* d_out, int out_size, void* d_ws, size_t ws_size,
                              hipStream_t stream) {
    const float* x       = (const float*)d_in[0];
    const float* values  = (const float*)d_in[1];
    const int*   col_idx = (const int*)d_in[2];
    float* out = (float*)d_out;

    const size_t wbytes = (size_t)M_DIM * H_DIM * sizeof(unsigned short);   // 33.5 MB
    const size_t xbytes = (size_t)N_ROWS * H_DIM * sizeof(unsigned short);  // 67 MB

    if (ws_size >= wbytes + xbytes) {
        unsigned short* Wf = (unsigned short*)d_ws;
        unsigned short* Xb = (unsigned short*)((char*)d_ws + wbytes);

        decode_w_frag_kernel<<<M_DIM / 4, 256, 0, stream>>>(values, col_idx, Wf);
        convert_x_kernel<<<4096, 256, 0, stream>>>(
            (const float4*)x, (unsigned long long*)Xb);
        gemm256_kernel<<<512, 512, 0, stream>>>(Xb, Wf, out);
    } else {
        naive_kernel<<<(int)((long)N_ROWS * M_DIM / 256), 256, 0, stream>>>(
            x, values, col_idx, out);
    }
}